// Round 14
// baseline (175.611 us; speedup 1.0000x reference)
//
#include <hip/hip_runtime.h>
#include <hip/hip_bf16.h>

typedef __bf16 bf16_t;
typedef __bf16 bf16x4 __attribute__((ext_vector_type(4)));
typedef __bf16 bf16x8 __attribute__((ext_vector_type(8)));
typedef float f32x4 __attribute__((ext_vector_type(4)));
typedef float f32x8 __attribute__((ext_vector_type(8)));

#define MFMA16(a, b, c) __builtin_amdgcn_mfma_f32_16x16x32_bf16(a, b, c, 0, 0, 0)

#define GLOAD_LDS16(g, l)                                              \
  __builtin_amdgcn_global_load_lds(                                    \
      (const __attribute__((address_space(1))) unsigned int*)(g),      \
      (__attribute__((address_space(3))) unsigned int*)(l), 16, 0, 0)

constexpr int B = 2, T = 2048, C = 1024, H = 16, D = 64;
constexpr int NQKV = 3 * C;   // 3072
constexpr int M = B * T;      // 4096

// Q is pre-scaled at QKV time by 1/sqrt(D) * log2(e) so attention's softmax
// is a bare exp2 of the MFMA score.
#define QSCALE 0.18033688011112042f

// ---------------------------------------------------------------------------
// Kernel 0: f32 -> bf16 convert (x, attn_w, proj_w).
// ---------------------------------------------------------------------------
__global__ __launch_bounds__(256) void cvt_kernel(
    const float* __restrict__ s0, bf16_t* __restrict__ d0, int n0,
    const float* __restrict__ s1, bf16_t* __restrict__ d1, int n1,
    const float* __restrict__ s2, bf16_t* __restrict__ d2, int n2)
{
  const float* s; bf16_t* d; int n;
  if (blockIdx.y == 0)      { s = s0; d = d0; n = n0; }
  else if (blockIdx.y == 1) { s = s1; d = d1; n = n1; }
  else                      { s = s2; d = d2; n = n2; }
  const int idx = (blockIdx.x * 256 + threadIdx.x) * 8;
  if (idx >= n) return;
  f32x8 t = *(const f32x8*)(s + idx);
  bf16x8 r;
#pragma unroll
  for (int j = 0; j < 8; ++j) r[j] = (bf16_t)t[j];
  *(bf16x8*)(d + idx) = r;
}

// ---------------------------------------------------------------------------
// GEMM mainloop: double-buffered LDS, one barrier per BK=64 iteration.
// ---------------------------------------------------------------------------
template<int BN, int NI>
__device__ __forceinline__ void gemm_mainloop_db(
    const bf16_t* __restrict__ A, const bf16_t* __restrict__ Wt,
    const int K, const int m0, const int n0,
    bf16_t* ldsA0, bf16_t* ldsA1, bf16_t* ldsB0, bf16_t* ldsB1,
    f32x4 acc[4][NI])
{
  const int tid  = threadIdx.x;
  const int wv   = tid >> 6;
  const int lane = tid & 63;
  const int col  = lane & 15;
  const int quad = lane >> 4;
  const int lr8  = lane >> 3;
  const int cpos = lane & 7;
  const int wm = wv >> 1, wn = wv & 1;
  constexpr int BJ = BN / 32;
  constexpr int BRW = BN / 4;

  const bf16_t* ag[4]; const bf16_t* bg[BJ];
#pragma unroll
  for (int j = 0; j < 4; ++j)
    ag[j] = A + (size_t)(m0 + wv * 32 + j * 8 + lr8) * K + (cpos ^ lr8) * 8;
#pragma unroll
  for (int j = 0; j < BJ; ++j)
    bg[j] = Wt + (size_t)(n0 + wv * BRW + j * 8 + lr8) * K + (cpos ^ lr8) * 8;

  const int xa = quad ^ (col & 7);
  const int niter = K / 64;

#pragma unroll
  for (int j = 0; j < 4; ++j)
    GLOAD_LDS16(ag[j], ldsA0 + (wv * 32 + j * 8) * 64);
#pragma unroll
  for (int j = 0; j < BJ; ++j)
    GLOAD_LDS16(bg[j], ldsB0 + (wv * BRW + j * 8) * 64);

  for (int it = 0; it < niter; ++it) {
    __syncthreads();
    const bf16_t* cA = (it & 1) ? ldsA1 : ldsA0;
    const bf16_t* cB = (it & 1) ? ldsB1 : ldsB0;
    if (it + 1 < niter) {
      bf16_t* nA = (it & 1) ? ldsA0 : ldsA1;
      bf16_t* nB = (it & 1) ? ldsB0 : ldsB1;
      const int off = (it + 1) * 64;
#pragma unroll
      for (int j = 0; j < 4; ++j)
        GLOAD_LDS16(ag[j] + off, nA + (wv * 32 + j * 8) * 64);
#pragma unroll
      for (int j = 0; j < BJ; ++j)
        GLOAD_LDS16(bg[j] + off, nB + (wv * BRW + j * 8) * 64);
    }
#pragma unroll
    for (int ks = 0; ks < 2; ++ks) {
      const int xk = (xa ^ (ks * 4)) * 8;
      bf16x8 af[4], bfr[NI];
#pragma unroll
      for (int mi = 0; mi < 4; ++mi)
        af[mi] = *(const bf16x8*)(cA + (wm * 64 + mi * 16 + col) * 64 + xk);
#pragma unroll
      for (int ni = 0; ni < NI; ++ni)
        bfr[ni] = *(const bf16x8*)(cB + (wn * (NI * 16) + ni * 16 + col) * 64 + xk);
#pragma unroll
      for (int mi = 0; mi < 4; ++mi)
#pragma unroll
        for (int ni = 0; ni < NI; ++ni)
          acc[mi][ni] = MFMA16(af[mi], bfr[ni], acc[mi][ni]);
    }
  }
}

// ---------------------------------------------------------------------------
// Kernel 1: QKV GEMM.  Q stores pre-scaled by QSCALE.  V: LDS-bounce
// transpose, keys permuted per 64-tile: sigma(t) = (t&15)*4 + ((t>>4)&3).
// ---------------------------------------------------------------------------
__global__ __launch_bounds__(256) void qkv_gemm_kernel(
    const bf16_t* __restrict__ x, const bf16_t* __restrict__ w,
    const float* __restrict__ bias,
    bf16_t* __restrict__ qws, bf16_t* __restrict__ kws, bf16_t* __restrict__ vws)
{
  __shared__ __align__(16) bf16_t ldsA[2][128 * 64];
  __shared__ __align__(16) bf16_t ldsB[2][128 * 64];
  const int lane = threadIdx.x & 63;
  const int wv   = threadIdx.x >> 6;
  const int col  = lane & 15;
  const int quad = lane >> 4;
  const int wm = wv >> 1, wn = wv & 1;
  const int m0 = blockIdx.y * 128;
  const int n0 = blockIdx.x * 128;

  f32x4 acc[4][4] = {};
  gemm_mainloop_db<128, 4>(x, w, C, m0, n0,
                           ldsA[0], ldsA[1], ldsB[0], ldsB[1], acc);

  const int which = n0 >> 10;

  if (which == 2) {
    __syncthreads();
    bf16_t* vt = &ldsA[0][0] + wv * 4096;

#pragma unroll
    for (int ni = 0; ni < 4; ++ni) {
      const int n = n0 + wn * 64 + ni * 16 + col;
      const float bval = bias[n];
      const int d = n & 63;
#pragma unroll
      for (int r = 0; r < 4; ++r) {
        bf16x4 pw;
#pragma unroll
        for (int mi = 0; mi < 4; ++mi)
          pw[mi] = (bf16_t)(acc[mi][ni][r] + bval);
        const int k = 2 * quad + (r >> 1);
        const int S = d * 8 + (k ^ (d & 7));
        *(bf16x4*)(vt + S * 8 + (r & 1) * 4) = pw;
      }
    }

    const int b   = (m0 + wm * 64) >> 11;
    const int t0w = (m0 + wm * 64) & (T - 1);
    const int h   = ((n0 & (C - 1)) + wn * 64) >> 6;
    const size_t bh = (size_t)(b * H + h);
    const int lr8 = lane >> 3;
    const int c8  = lane & 7;
#pragma unroll
    for (int j = 0; j < 8; ++j) {
      const int d = j * 8 + lr8;
      bf16x8 row = *(const bf16x8*)(vt + (d * 8 + (c8 ^ (d & 7))) * 8);
      *(bf16x8*)(vws + (bh * D + d) * T + t0w + c8 * 8) = row;
    }
  } else {
#pragma unroll
    for (int ni = 0; ni < 4; ++ni) {
      const int n = n0 + wn * 64 + ni * 16 + col;
      const float bval = bias[n];
      const int c = n & (C - 1);
      const int h = c >> 6;
      const int d = c & 63;
#pragma unroll
      for (int mi = 0; mi < 4; ++mi) {
#pragma unroll
        for (int r = 0; r < 4; ++r) {
          const int m = m0 + wm * 64 + mi * 16 + quad * 4 + r;
          const int b = m >> 11;
          const int t = m & (T - 1);
          const size_t bh = (size_t)(b * H + h);
          if (which == 0)
            qws[(bh * T + t) * D + d] = (bf16_t)((acc[mi][ni][r] + bval) * QSCALE);
          else
            kws[(bh * T + t) * D + d] = (bf16_t)(acc[mi][ni][r] + bval);
        }
      }
    }
  }
}

// ---------------------------------------------------------------------------
// Kernel 2: causal flash attention v7.
//  - XCD-local 1D grid (bh = id & 31), merged dual-tile sweep (33 units).
//  - HOISTED kf/vf: K and V fragments are identical for the heavy and light
//    tiles -> read once per iteration, feed both accumulators (dual-iter
//    LDS reads 36 -> 20 b128; ~10 us of CU-serialized LDS issue saved).
//  - Two wave-private P regions (no WAR hazard between tiles).
//  - Q pre-scaled at QKV time: p = exp2(score) directly.
// ---------------------------------------------------------------------------
__global__ __launch_bounds__(256, 2) void attn_kernel(
    const bf16_t* __restrict__ qws, const bf16_t* __restrict__ kws,
    const bf16_t* __restrict__ vws, bf16_t* __restrict__ yws)
{
  const int id = blockIdx.x;
  const int bh = id & 31;
  const int pr = id >> 5;            // 0..15
  const int tid  = threadIdx.x;
  const int wv   = tid >> 6;
  const int lane = tid & 63;
  const int col  = lane & 15;
  const int quad = lane >> 4;

  const bf16_t* Q  = qws + (size_t)bh * T * D;
  const bf16_t* K  = kws + (size_t)bh * T * D;
  const bf16_t* Vt = vws + (size_t)bh * D * T;

  __shared__ __align__(16) bf16_t ldsK[2][64 * 64];
  __shared__ __align__(16) bf16_t ldsV[2][64 * 64];
  __shared__ __align__(16) bf16_t ldsP[8][16 * 64];
  bf16_t* ldsPh = ldsP[wv * 2];
  bf16_t* ldsPl = ldsP[wv * 2 + 1];

  const int xs   = col & 7;
  const int cxq  = (quad ^ xs) * 8;
  const int lr8  = lane >> 3;
  const int ksrc = (lane & 7) ^ lr8;
  const int pxor = (quad & 1) * 4;
  const int b = bh >> 4;
  const int h = bh & 15;

  const int qt_h = 31 - pr, qt_l = pr;       // qt_l < qt_h always
  const int t0h = qt_h * 64, t0l = qt_l * 64;
  const int twh = t0h + 16 * wv, twl = t0l + 16 * wv;
  const int niter = qt_h + 1;

  bf16x8 qfh0 = *(const bf16x8*)(Q + (size_t)(twh + col) * D + quad * 8);
  bf16x8 qfh1 = *(const bf16x8*)(Q + (size_t)(twh + col) * D + 32 + quad * 8);
  bf16x8 qfl0 = *(const bf16x8*)(Q + (size_t)(twl + col) * D + quad * 8);
  bf16x8 qfl1 = *(const bf16x8*)(Q + (size_t)(twl + col) * D + 32 + quad * 8);

  f32x4 oh[4] = {}, ol[4] = {};
  f32x4 lph = {}, lpl = {};

  // prologue: stage tile 0 into buffer 0
#pragma unroll
  for (int j = 0; j < 2; ++j) {
    GLOAD_LDS16(K + (size_t)(16 * wv + j * 8 + lr8) * D + ksrc * 8,
                ldsK[0] + (16 * wv + j * 8) * 64);
    GLOAD_LDS16(Vt + (size_t)(16 * wv + j * 8 + lr8) * T + ksrc * 8,
                ldsV[0] + (16 * wv + j * 8) * 64);
  }

  for (int it = 0; it < niter; ++it) {
    const int s0 = it * 64;
    __syncthreads();

    if (it + 1 < niter) {
      const int sn = s0 + 64;
      bf16_t* dK = ldsK[(it + 1) & 1];
      bf16_t* dV = ldsV[(it + 1) & 1];
#pragma unroll
      for (int j = 0; j < 2; ++j) {
        GLOAD_LDS16(K + (size_t)(sn + 16 * wv + j * 8 + lr8) * D + ksrc * 8,
                    dK + (16 * wv + j * 8) * 64);
        GLOAD_LDS16(Vt + (size_t)(16 * wv + j * 8 + lr8) * T + sn + ksrc * 8,
                    dV + (16 * wv + j * 8) * 64);
      }
    }

    const bf16_t* bK = ldsK[it & 1];
    const bf16_t* bV = ldsV[it & 1];
    const bool dual = (s0 <= t0l);

    // --- QK^T for both tiles, kf read ONCE ---
    f32x4 sch[4], scl[4];
#pragma unroll
    for (int kb = 0; kb < 4; ++kb) {
      const bf16_t* kr = bK + (kb * 16 + col) * 64;
      bf16x8 kf0 = *(const bf16x8*)(kr + cxq);
      bf16x8 kf1 = *(const bf16x8*)(kr + (cxq ^ 32));
      f32x4 a = {};
      a = MFMA16(qfh0, kf0, a);
      a = MFMA16(qfh1, kf1, a);
      sch[kb] = a;
      if (dual) {
        f32x4 al = {};
        al = MFMA16(qfl0, kf0, al);
        al = MFMA16(qfl1, kf1, al);
        scl[kb] = al;
      }
    }

    // --- softmax + P writes (heavy) ---
    {
      const bool diag = (s0 == t0h);
#pragma unroll
      for (int r = 0; r < 4; ++r) {
        const int prow = (quad * 4 + r) * 64;
        const int pxr  = pxor + r;
        bf16x4 pw;
#pragma unroll
        for (int kb = 0; kb < 4; ++kb) {
          float p = __builtin_amdgcn_exp2f(sch[kb][r]);
          if (diag && (s0 + kb * 16 + col > twh + quad * 4 + r)) p = 0.0f;
          lph[r] += p;
          pw[kb] = (bf16_t)p;
        }
        *(bf16x4*)(ldsPh + prow + (((col >> 1) ^ pxr) * 8) + (col & 1) * 4) = pw;
      }
    }
    // --- softmax + P writes (light) ---
    if (dual) {
      const bool diag = (s0 == t0l);
#pragma unroll
      for (int r = 0; r < 4; ++r) {
        const int prow = (quad * 4 + r) * 64;
        const int pxr  = pxor + r;
        bf16x4 pw;
#pragma unroll
        for (int kb = 0; kb < 4; ++kb) {
          float p = __builtin_amdgcn_exp2f(scl[kb][r]);
          if (diag && (s0 + kb * 16 + col > twl + quad * 4 + r)) p = 0.0f;
          lpl[r] += p;
          pw[kb] = (bf16_t)p;
        }
        *(bf16x4*)(ldsPl + prow + (((col >> 1) ^ pxr) * 8) + (col & 1) * 4) = pw;
      }
    }

    // --- PV for both tiles, vf read ONCE ---
#pragma unroll
    for (int ks = 0; ks < 2; ++ks) {
      const int xk = cxq ^ (ks * 32);
      bf16x8 pah = *(const bf16x8*)(ldsPh + col * 64 + xk);
      if (dual) {
        bf16x8 pal = *(const bf16x8*)(ldsPl + col * 64 + xk);
#pragma unroll
        for (int ni = 0; ni < 4; ++ni) {
          bf16x8 vf = *(const bf16x8*)(bV + (ni * 16 + col) * 64 + xk);
          oh[ni] = MFMA16(pah, vf, oh[ni]);
          ol[ni] = MFMA16(pal, vf, ol[ni]);
        }
      } else {
#pragma unroll
        for (int ni = 0; ni < 4; ++ni) {
          bf16x8 vf = *(const bf16x8*)(bV + (ni * 16 + col) * 64 + xk);
          oh[ni] = MFMA16(pah, vf, oh[ni]);
        }
      }
    }
  }

  // epilogue: reduce l, normalize, write Y for both tiles
#pragma unroll
  for (int r = 0; r < 4; ++r) {
    float l0 = lph[r], l1 = lpl[r];
#pragma unroll
    for (int off = 1; off < 16; off <<= 1) {
      l0 += __shfl_xor(l0, off);
      l1 += __shfl_xor(l1, off);
    }
    const float rl0 = 1.0f / l0, rl1 = 1.0f / l1;
    const int th = twh + quad * 4 + r;
    const int tl = twl + quad * 4 + r;
#pragma unroll
    for (int ni = 0; ni < 4; ++ni) {
      const int d = ni * 16 + col;
      yws[((size_t)(b * T + th)) * C + h * D + d] = (bf16_t)(oh[ni][r] * rl0);
      yws[((size_t)(b * T + tl)) * C + h * D + d] = (bf16_t)(ol[ni][r] * rl1);
    }
  }
}

// ---------------------------------------------------------------------------
// Kernel 3: output projection — 128x64 tile, dbuf mainloop, f32 output.
// ---------------------------------------------------------------------------
__global__ __launch_bounds__(256) void proj_gemm_kernel(
    const bf16_t* __restrict__ y, const bf16_t* __restrict__ w,
    const float* __restrict__ bias, float* __restrict__ out)
{
  __shared__ __align__(16) bf16_t ldsA[2][128 * 64];
  __shared__ __align__(16) bf16_t ldsB[2][64 * 64];
  const int lane = threadIdx.x & 63;
  const int wv   = threadIdx.x >> 6;
  const int col  = lane & 15;
  const int quad = lane >> 4;
  const int wm = wv >> 1, wn = wv & 1;
  const int m0 = blockIdx.y * 128;
  const int n0 = blockIdx.x * 64;

  f32x4 acc[4][2] = {};
  gemm_mainloop_db<64, 2>(y, w, C, m0, n0,
                          ldsA[0], ldsA[1], ldsB[0], ldsB[1], acc);

#pragma unroll
  for (int ni = 0; ni < 2; ++ni) {
    const int n = n0 + wn * 32 + ni * 16 + col;
    const float bval = bias[n];
#pragma unroll
    for (int mi = 0; mi < 4; ++mi) {
#pragma unroll
      for (int r = 0; r < 4; ++r) {
        const int m = m0 + wm * 64 + mi * 16 + quad * 4 + r;
        out[(size_t)m * C + n] = acc[mi][ni][r] + bval;
      }
    }
  }
}

// ---------------------------------------------------------------------------
extern "C" void kernel_launch(void* const* d_in, const int* in_sizes, int n_in,
                              void* d_out, int out_size, void* d_ws, size_t ws_size,
                              hipStream_t stream) {
  const float* x      = (const float*)d_in[0];
  const float* attn_w = (const float*)d_in[1];
  const float* attn_b = (const float*)d_in[2];
  const float* proj_w = (const float*)d_in[3];
  const float* proj_b = (const float*)d_in[4];
  float* out = (float*)d_out;

  const size_t E = (size_t)B * H * T * D;   // 4,194,304
  char* ws = (char*)d_ws;
  bf16_t* qws = (bf16_t*)(ws);
  bf16_t* kws = (bf16_t*)(ws + 2 * E);
  bf16_t* vws = (bf16_t*)(ws + 4 * E);
  bf16_t* yws = (bf16_t*)(ws + 6 * E);
  bf16_t* xb  = (bf16_t*)(ws + 8 * E);
  bf16_t* awb = (bf16_t*)(ws + 10 * E);
  bf16_t* pwb = (bf16_t*)(ws + 11 * E + E / 2);

  const int NX = M * C, NAW = NQKV * C, NPW = C * C;
  cvt_kernel<<<dim3(NX / 2048, 3), 256, 0, stream>>>(
      x, xb, NX, attn_w, awb, NAW, proj_w, pwb, NPW);
  qkv_gemm_kernel<<<dim3(NQKV / 128, M / 128), 256, 0, stream>>>(
      xb, awb, attn_b, qws, kws, vws);
  attn_kernel<<<512, 256, 0, stream>>>(qws, kws, vws, yws);
  proj_gemm_kernel<<<dim3(C / 64, M / 128), 256, 0, stream>>>(
      yws, pwb, proj_b, out);
}

// Round 15
// 169.975 us; speedup vs baseline: 1.0332x; 1.0332x over previous
//
#include <hip/hip_runtime.h>
#include <hip/hip_bf16.h>

typedef __bf16 bf16_t;
typedef __bf16 bf16x4 __attribute__((ext_vector_type(4)));
typedef __bf16 bf16x8 __attribute__((ext_vector_type(8)));
typedef float f32x4 __attribute__((ext_vector_type(4)));
typedef float f32x8 __attribute__((ext_vector_type(8)));

#define MFMA16(a, b, c) __builtin_amdgcn_mfma_f32_16x16x32_bf16(a, b, c, 0, 0, 0)

#define GLOAD_LDS16(g, l)                                              \
  __builtin_amdgcn_global_load_lds(                                    \
      (const __attribute__((address_space(1))) unsigned int*)(g),      \
      (__attribute__((address_space(3))) unsigned int*)(l), 16, 0, 0)

constexpr int B = 2, T = 2048, C = 1024, H = 16, D = 64;
constexpr int NQKV = 3 * C;   // 3072
constexpr int M = B * T;      // 4096

// Q pre-scaled at QKV time by 1/sqrt(D)*log2(e): attn softmax = bare exp2.
#define QSCALE 0.18033688011112042f

// ---------------------------------------------------------------------------
// Kernel 0: f32 -> bf16 convert (x, attn_w, proj_w).
// ---------------------------------------------------------------------------
__global__ __launch_bounds__(256) void cvt_kernel(
    const float* __restrict__ s0, bf16_t* __restrict__ d0, int n0,
    const float* __restrict__ s1, bf16_t* __restrict__ d1, int n1,
    const float* __restrict__ s2, bf16_t* __restrict__ d2, int n2)
{
  const float* s; bf16_t* d; int n;
  if (blockIdx.y == 0)      { s = s0; d = d0; n = n0; }
  else if (blockIdx.y == 1) { s = s1; d = d1; n = n1; }
  else                      { s = s2; d = d2; n = n2; }
  const int idx = (blockIdx.x * 256 + threadIdx.x) * 8;
  if (idx >= n) return;
  f32x8 t = *(const f32x8*)(s + idx);
  bf16x8 r;
#pragma unroll
  for (int j = 0; j < 8; ++j) r[j] = (bf16_t)t[j];
  *(bf16x8*)(d + idx) = r;
}

// ---------------------------------------------------------------------------
// GEMM mainloop (generalized): BM x BN block tile, double-buffered LDS, one
// barrier per BK=64 iteration, XOR chunk swizzle, width-16 global_load_lds.
// 4 waves as 2x2; wave tile (MI*16) x (NI*16).
// ---------------------------------------------------------------------------
template<int BM, int BN, int MI, int NI>
__device__ __forceinline__ void gemm_mainloop_db(
    const bf16_t* __restrict__ A, const bf16_t* __restrict__ Wt,
    const int K, const int m0, const int n0,
    bf16_t* ldsA0, bf16_t* ldsA1, bf16_t* ldsB0, bf16_t* ldsB1,
    f32x4 acc[MI][NI])
{
  const int tid  = threadIdx.x;
  const int wv   = tid >> 6;
  const int lane = tid & 63;
  const int col  = lane & 15;
  const int quad = lane >> 4;
  const int lr8  = lane >> 3;
  const int cpos = lane & 7;
  const int wm = wv >> 1, wn = wv & 1;
  constexpr int AJ = BM / 32;          // A staging instrs per wave
  constexpr int ARW = BM / 4;          // A rows per wave
  constexpr int BJ = BN / 32;
  constexpr int BRW = BN / 4;

  const bf16_t* ag[AJ]; const bf16_t* bg[BJ];
#pragma unroll
  for (int j = 0; j < AJ; ++j)
    ag[j] = A + (size_t)(m0 + wv * ARW + j * 8 + lr8) * K + (cpos ^ lr8) * 8;
#pragma unroll
  for (int j = 0; j < BJ; ++j)
    bg[j] = Wt + (size_t)(n0 + wv * BRW + j * 8 + lr8) * K + (cpos ^ lr8) * 8;

  const int xa = quad ^ (col & 7);
  const int niter = K / 64;

#pragma unroll
  for (int j = 0; j < AJ; ++j)
    GLOAD_LDS16(ag[j], ldsA0 + (wv * ARW + j * 8) * 64);
#pragma unroll
  for (int j = 0; j < BJ; ++j)
    GLOAD_LDS16(bg[j], ldsB0 + (wv * BRW + j * 8) * 64);

  for (int it = 0; it < niter; ++it) {
    __syncthreads();
    const bf16_t* cA = (it & 1) ? ldsA1 : ldsA0;
    const bf16_t* cB = (it & 1) ? ldsB1 : ldsB0;
    if (it + 1 < niter) {
      bf16_t* nA = (it & 1) ? ldsA0 : ldsA1;
      bf16_t* nB = (it & 1) ? ldsB0 : ldsB1;
      const int off = (it + 1) * 64;
#pragma unroll
      for (int j = 0; j < AJ; ++j)
        GLOAD_LDS16(ag[j] + off, nA + (wv * ARW + j * 8) * 64);
#pragma unroll
      for (int j = 0; j < BJ; ++j)
        GLOAD_LDS16(bg[j] + off, nB + (wv * BRW + j * 8) * 64);
    }
#pragma unroll
    for (int ks = 0; ks < 2; ++ks) {
      const int xk = (xa ^ (ks * 4)) * 8;
      bf16x8 af[MI], bfr[NI];
#pragma unroll
      for (int mi = 0; mi < MI; ++mi)
        af[mi] = *(const bf16x8*)(cA + (wm * (MI * 16) + mi * 16 + col) * 64 + xk);
#pragma unroll
      for (int ni = 0; ni < NI; ++ni)
        bfr[ni] = *(const bf16x8*)(cB + (wn * (NI * 16) + ni * 16 + col) * 64 + xk);
#pragma unroll
      for (int mi = 0; mi < MI; ++mi)
#pragma unroll
        for (int ni = 0; ni < NI; ++ni)
          acc[mi][ni] = MFMA16(af[mi], bfr[ni], acc[mi][ni]);
    }
  }
}

// ---------------------------------------------------------------------------
// Kernel 1: QKV GEMM (round-13 structure).  Q stores pre-scaled by QSCALE.
// V: LDS-bounce transpose, keys permuted per 64-tile:
// sigma(t) = (t&15)*4 + ((t>>4)&3).
// ---------------------------------------------------------------------------
__global__ __launch_bounds__(256) void qkv_gemm_kernel(
    const bf16_t* __restrict__ x, const bf16_t* __restrict__ w,
    const float* __restrict__ bias,
    bf16_t* __restrict__ qws, bf16_t* __restrict__ kws, bf16_t* __restrict__ vws)
{
  __shared__ __align__(16) bf16_t ldsA[2][128 * 64];
  __shared__ __align__(16) bf16_t ldsB[2][128 * 64];
  const int lane = threadIdx.x & 63;
  const int wv   = threadIdx.x >> 6;
  const int col  = lane & 15;
  const int quad = lane >> 4;
  const int wm = wv >> 1, wn = wv & 1;
  const int m0 = blockIdx.y * 128;
  const int n0 = blockIdx.x * 128;

  f32x4 acc[4][4] = {};
  gemm_mainloop_db<128, 128, 4, 4>(x, w, C, m0, n0,
                                   ldsA[0], ldsA[1], ldsB[0], ldsB[1], acc);

  const int which = n0 >> 10;

  if (which == 2) {
    __syncthreads();
    bf16_t* vt = &ldsA[0][0] + wv * 4096;

#pragma unroll
    for (int ni = 0; ni < 4; ++ni) {
      const int n = n0 + wn * 64 + ni * 16 + col;
      const float bval = bias[n];
      const int d = n & 63;
#pragma unroll
      for (int r = 0; r < 4; ++r) {
        bf16x4 pw;
#pragma unroll
        for (int mi = 0; mi < 4; ++mi)
          pw[mi] = (bf16_t)(acc[mi][ni][r] + bval);
        const int k = 2 * quad + (r >> 1);
        const int S = d * 8 + (k ^ (d & 7));
        *(bf16x4*)(vt + S * 8 + (r & 1) * 4) = pw;
      }
    }

    const int b   = (m0 + wm * 64) >> 11;
    const int t0w = (m0 + wm * 64) & (T - 1);
    const int h   = ((n0 & (C - 1)) + wn * 64) >> 6;
    const size_t bh = (size_t)(b * H + h);
    const int lr8 = lane >> 3;
    const int c8  = lane & 7;
#pragma unroll
    for (int j = 0; j < 8; ++j) {
      const int d = j * 8 + lr8;
      bf16x8 row = *(const bf16x8*)(vt + (d * 8 + (c8 ^ (d & 7))) * 8);
      *(bf16x8*)(vws + (bh * D + d) * T + t0w + c8 * 8) = row;
    }
  } else {
#pragma unroll
    for (int ni = 0; ni < 4; ++ni) {
      const int n = n0 + wn * 64 + ni * 16 + col;
      const float bval = bias[n];
      const int c = n & (C - 1);
      const int h = c >> 6;
      const int d = c & 63;
#pragma unroll
      for (int mi = 0; mi < 4; ++mi) {
#pragma unroll
        for (int r = 0; r < 4; ++r) {
          const int m = m0 + wm * 64 + mi * 16 + quad * 4 + r;
          const int b = m >> 11;
          const int t = m & (T - 1);
          const size_t bh = (size_t)(b * H + h);
          if (which == 0)
            qws[(bh * T + t) * D + d] = (bf16_t)((acc[mi][ni][r] + bval) * QSCALE);
          else
            kws[(bh * T + t) * D + d] = (bf16_t)(acc[mi][ni][r] + bval);
        }
      }
    }
  }
}

// ---------------------------------------------------------------------------
// Kernel 2: causal flash attention — round-13 v6 structure (sequential
// compute_tile per tile; that shape gave 46.5 us; the r14 hoisted merge
// regressed to 52.5 by serializing the dependency chain).  Two micro-deltas:
//  - Q pre-scaled: exp2(score) directly (16 fewer v_mul per tile).
//  - wave-uniform diag branch: masked softmax path only on each tile's
//    final (diagonal) iteration.
// ---------------------------------------------------------------------------
__global__ __launch_bounds__(256) void attn_kernel(
    const bf16_t* __restrict__ qws, const bf16_t* __restrict__ kws,
    const bf16_t* __restrict__ vws, bf16_t* __restrict__ yws)
{
  const int id = blockIdx.x;
  const int bh = id & 31;
  const int pr = id >> 5;            // 0..15
  const int tid  = threadIdx.x;
  const int wv   = tid >> 6;
  const int lane = tid & 63;
  const int col  = lane & 15;
  const int quad = lane >> 4;

  const bf16_t* Q  = qws + (size_t)bh * T * D;
  const bf16_t* K  = kws + (size_t)bh * T * D;
  const bf16_t* Vt = vws + (size_t)bh * D * T;

  __shared__ __align__(16) bf16_t ldsK[2][64 * 64];
  __shared__ __align__(16) bf16_t ldsV[2][64 * 64];
  __shared__ __align__(16) bf16_t ldsP[4][16 * 64];
  bf16_t* ldsPw = ldsP[wv];

  const int xs   = col & 7;
  const int cxq  = (quad ^ xs) * 8;
  const int lr8  = lane >> 3;
  const int ksrc = (lane & 7) ^ lr8;
  const int pxor = (quad & 1) * 4;
  const int b = bh >> 4;
  const int h = bh & 15;

  const int qt_h = 31 - pr, qt_l = pr;       // qt_l < qt_h always
  const int t0h = qt_h * 64, t0l = qt_l * 64;
  const int twh = t0h + 16 * wv, twl = t0l + 16 * wv;
  const int niter = qt_h + 1;

  bf16x8 qfh0 = *(const bf16x8*)(Q + (size_t)(twh + col) * D + quad * 8);
  bf16x8 qfh1 = *(const bf16x8*)(Q + (size_t)(twh + col) * D + 32 + quad * 8);
  bf16x8 qfl0 = *(const bf16x8*)(Q + (size_t)(twl + col) * D + quad * 8);
  bf16x8 qfl1 = *(const bf16x8*)(Q + (size_t)(twl + col) * D + 32 + quad * 8);

  f32x4 oh[4] = {}, ol[4] = {};
  f32x4 lph = {}, lpl = {};

  // one compute unit: QK^T -> exp2 -> P to LDS -> PV accumulate
  auto compute_tile = [&](const bf16_t* bK, const bf16_t* bV, int s0, int tw,
                          int t0, bf16x8 qf0, bf16x8 qf1,
                          f32x4 (&o)[4], f32x4& lp) {
    f32x4 sc[4];
#pragma unroll
    for (int kb = 0; kb < 4; ++kb) {
      const bf16_t* kr = bK + (kb * 16 + col) * 64;
      bf16x8 kf0 = *(const bf16x8*)(kr + cxq);
      bf16x8 kf1 = *(const bf16x8*)(kr + (cxq ^ 32));
      f32x4 a = {};
      a = MFMA16(qf0, kf0, a);
      a = MFMA16(qf1, kf1, a);
      sc[kb] = a;
    }
    if (s0 == t0) {          // diagonal tile: masked softmax (uniform branch)
#pragma unroll
      for (int r = 0; r < 4; ++r) {
        const int prow = (quad * 4 + r) * 64;
        const int pxr  = pxor + r;
        bf16x4 pw;
#pragma unroll
        for (int kb = 0; kb < 4; ++kb) {
          float p = __builtin_amdgcn_exp2f(sc[kb][r]);
          if (s0 + kb * 16 + col > tw + quad * 4 + r) p = 0.0f;
          lp[r] += p;
          pw[kb] = (bf16_t)p;
        }
        *(bf16x4*)(ldsPw + prow + (((col >> 1) ^ pxr) * 8) + (col & 1) * 4) = pw;
      }
    } else {                 // interior tile: clean path
#pragma unroll
      for (int r = 0; r < 4; ++r) {
        const int prow = (quad * 4 + r) * 64;
        const int pxr  = pxor + r;
        bf16x4 pw;
#pragma unroll
        for (int kb = 0; kb < 4; ++kb) {
          float p = __builtin_amdgcn_exp2f(sc[kb][r]);
          lp[r] += p;
          pw[kb] = (bf16_t)p;
        }
        *(bf16x4*)(ldsPw + prow + (((col >> 1) ^ pxr) * 8) + (col & 1) * 4) = pw;
      }
    }
#pragma unroll
    for (int ks = 0; ks < 2; ++ks) {
      const int xk = cxq ^ (ks * 32);
      bf16x8 pa = *(const bf16x8*)(ldsPw + col * 64 + xk);
#pragma unroll
      for (int ni = 0; ni < 4; ++ni) {
        bf16x8 vf = *(const bf16x8*)(bV + (ni * 16 + col) * 64 + xk);
        o[ni] = MFMA16(pa, vf, o[ni]);
      }
    }
  };

  // prologue: stage tile 0 into buffer 0
#pragma unroll
  for (int j = 0; j < 2; ++j) {
    GLOAD_LDS16(K + (size_t)(16 * wv + j * 8 + lr8) * D + ksrc * 8,
                ldsK[0] + (16 * wv + j * 8) * 64);
    GLOAD_LDS16(Vt + (size_t)(16 * wv + j * 8 + lr8) * T + ksrc * 8,
                ldsV[0] + (16 * wv + j * 8) * 64);
  }

  for (int it = 0; it < niter; ++it) {
    const int s0 = it * 64;
    __syncthreads();

    if (it + 1 < niter) {
      const int sn = s0 + 64;
      bf16_t* dK = ldsK[(it + 1) & 1];
      bf16_t* dV = ldsV[(it + 1) & 1];
#pragma unroll
      for (int j = 0; j < 2; ++j) {
        GLOAD_LDS16(K + (size_t)(sn + 16 * wv + j * 8 + lr8) * D + ksrc * 8,
                    dK + (16 * wv + j * 8) * 64);
        GLOAD_LDS16(Vt + (size_t)(16 * wv + j * 8 + lr8) * T + sn + ksrc * 8,
                    dV + (16 * wv + j * 8) * 64);
      }
    }

    const bf16_t* bK = ldsK[it & 1];
    const bf16_t* bV = ldsV[it & 1];

    compute_tile(bK, bV, s0, twh, t0h, qfh0, qfh1, oh, lph);
    if (s0 <= t0l)
      compute_tile(bK, bV, s0, twl, t0l, qfl0, qfl1, ol, lpl);
  }

  // epilogue: reduce l, normalize, write Y for both tiles
#pragma unroll
  for (int r = 0; r < 4; ++r) {
    float l0 = lph[r], l1 = lpl[r];
#pragma unroll
    for (int off = 1; off < 16; off <<= 1) {
      l0 += __shfl_xor(l0, off);
      l1 += __shfl_xor(l1, off);
    }
    const float rl0 = 1.0f / l0, rl1 = 1.0f / l1;
    const int th = twh + quad * 4 + r;
    const int tl = twl + quad * 4 + r;
#pragma unroll
    for (int ni = 0; ni < 4; ++ni) {
      const int d = ni * 16 + col;
      yws[((size_t)(b * T + th)) * C + h * D + d] = (bf16_t)(oh[ni][r] * rl0);
      yws[((size_t)(b * T + tl)) * C + h * D + d] = (bf16_t)(ol[ni][r] * rl1);
    }
  }
}

// ---------------------------------------------------------------------------
// Kernel 3: output projection — 64x64 tiles (1024 blocks = 4/CU, 32 KB LDS)
// to hide the latency-bound K-loop; dbuf mainloop; f32 output.
// ---------------------------------------------------------------------------
__global__ __launch_bounds__(256) void proj_gemm_kernel(
    const bf16_t* __restrict__ y, const bf16_t* __restrict__ w,
    const float* __restrict__ bias, float* __restrict__ out)
{
  __shared__ __align__(16) bf16_t ldsA[2][64 * 64];
  __shared__ __align__(16) bf16_t ldsB[2][64 * 64];
  const int lane = threadIdx.x & 63;
  const int wv   = threadIdx.x >> 6;
  const int col  = lane & 15;
  const int quad = lane >> 4;
  const int wm = wv >> 1, wn = wv & 1;
  const int m0 = blockIdx.y * 64;
  const int n0 = blockIdx.x * 64;

  f32x4 acc[2][2] = {};
  gemm_mainloop_db<64, 64, 2, 2>(y, w, C, m0, n0,
                                 ldsA[0], ldsA[1], ldsB[0], ldsB[1], acc);

#pragma unroll
  for (int ni = 0; ni < 2; ++ni) {
    const int n = n0 + wn * 32 + ni * 16 + col;
    const float bval = bias[n];
#pragma unroll
    for (int mi = 0; mi < 2; ++mi) {
#pragma unroll
      for (int r = 0; r < 4; ++r) {
        const int m = m0 + wm * 32 + mi * 16 + quad * 4 + r;
        out[(size_t)m * C + n] = acc[mi][ni][r] + bval;
      }
    }
  }
}

// ---------------------------------------------------------------------------
extern "C" void kernel_launch(void* const* d_in, const int* in_sizes, int n_in,
                              void* d_out, int out_size, void* d_ws, size_t ws_size,
                              hipStream_t stream) {
  const float* x      = (const float*)d_in[0];
  const float* attn_w = (const float*)d_in[1];
  const float* attn_b = (const float*)d_in[2];
  const float* proj_w = (const float*)d_in[3];
  const float* proj_b = (const float*)d_in[4];
  float* out = (float*)d_out;

  const size_t E = (size_t)B * H * T * D;   // 4,194,304
  char* ws = (char*)d_ws;
  bf16_t* qws = (bf16_t*)(ws);
  bf16_t* kws = (bf16_t*)(ws + 2 * E);
  bf16_t* vws = (bf16_t*)(ws + 4 * E);
  bf16_t* yws = (bf16_t*)(ws + 6 * E);
  bf16_t* xb  = (bf16_t*)(ws + 8 * E);
  bf16_t* awb = (bf16_t*)(ws + 10 * E);
  bf16_t* pwb = (bf16_t*)(ws + 11 * E + E / 2);

  const int NX = M * C, NAW = NQKV * C, NPW = C * C;
  cvt_kernel<<<dim3(NX / 2048, 3), 256, 0, stream>>>(
      x, xb, NX, attn_w, awb, NAW, proj_w, pwb, NPW);
  qkv_gemm_kernel<<<dim3(NQKV / 128, M / 128), 256, 0, stream>>>(
      xb, awb, attn_b, qws, kws, vws);
  attn_kernel<<<512, 256, 0, stream>>>(qws, kws, vws, yws);
  proj_gemm_kernel<<<dim3(C / 64, M / 64), 256, 0, stream>>>(
      yws, pwb, proj_b, out);
}

// Round 16
// 167.924 us; speedup vs baseline: 1.0458x; 1.0122x over previous
//
#include <hip/hip_runtime.h>
#include <hip/hip_bf16.h>

typedef __bf16 bf16_t;
typedef __bf16 bf16x4 __attribute__((ext_vector_type(4)));
typedef __bf16 bf16x8 __attribute__((ext_vector_type(8)));
typedef float f32x4 __attribute__((ext_vector_type(4)));
typedef float f32x8 __attribute__((ext_vector_type(8)));

#define MFMA16(a, b, c) __builtin_amdgcn_mfma_f32_16x16x32_bf16(a, b, c, 0, 0, 0)

#define GLOAD_LDS16(g, l)                                              \
  __builtin_amdgcn_global_load_lds(                                    \
      (const __attribute__((address_space(1))) unsigned int*)(g),      \
      (__attribute__((address_space(3))) unsigned int*)(l), 16, 0, 0)

constexpr int B = 2, T = 2048, C = 1024, H = 16, D = 64;
constexpr int NQKV = 3 * C;   // 3072
constexpr int M = B * T;      // 4096

// Q pre-scaled at QKV time by 1/sqrt(D)*log2(e): attn softmax = bare exp2.
#define QSCALE 0.18033688011112042f

// ---------------------------------------------------------------------------
// Kernel 0: f32 -> bf16 convert (x, attn_w, proj_w).
// ---------------------------------------------------------------------------
__global__ __launch_bounds__(256) void cvt_kernel(
    const float* __restrict__ s0, bf16_t* __restrict__ d0, int n0,
    const float* __restrict__ s1, bf16_t* __restrict__ d1, int n1,
    const float* __restrict__ s2, bf16_t* __restrict__ d2, int n2)
{
  const float* s; bf16_t* d; int n;
  if (blockIdx.y == 0)      { s = s0; d = d0; n = n0; }
  else if (blockIdx.y == 1) { s = s1; d = d1; n = n1; }
  else                      { s = s2; d = d2; n = n2; }
  const int idx = (blockIdx.x * 256 + threadIdx.x) * 8;
  if (idx >= n) return;
  f32x8 t = *(const f32x8*)(s + idx);
  bf16x8 r;
#pragma unroll
  for (int j = 0; j < 8; ++j) r[j] = (bf16_t)t[j];
  *(bf16x8*)(d + idx) = r;
}

// ---------------------------------------------------------------------------
// GEMM mainloop (generalized): BM x BN block tile, double-buffered LDS, one
// barrier per BK=64 iteration, XOR chunk swizzle, width-16 global_load_lds.
// 4 waves as 2x2; wave tile (MI*16) x (NI*16).
// ---------------------------------------------------------------------------
template<int BM, int BN, int MI, int NI>
__device__ __forceinline__ void gemm_mainloop_db(
    const bf16_t* __restrict__ A, const bf16_t* __restrict__ Wt,
    const int K, const int m0, const int n0,
    bf16_t* ldsA0, bf16_t* ldsA1, bf16_t* ldsB0, bf16_t* ldsB1,
    f32x4 acc[MI][NI])
{
  const int tid  = threadIdx.x;
  const int wv   = tid >> 6;
  const int lane = tid & 63;
  const int col  = lane & 15;
  const int quad = lane >> 4;
  const int lr8  = lane >> 3;
  const int cpos = lane & 7;
  const int wm = wv >> 1, wn = wv & 1;
  constexpr int AJ = BM / 32;
  constexpr int ARW = BM / 4;
  constexpr int BJ = BN / 32;
  constexpr int BRW = BN / 4;

  const bf16_t* ag[AJ]; const bf16_t* bg[BJ];
#pragma unroll
  for (int j = 0; j < AJ; ++j)
    ag[j] = A + (size_t)(m0 + wv * ARW + j * 8 + lr8) * K + (cpos ^ lr8) * 8;
#pragma unroll
  for (int j = 0; j < BJ; ++j)
    bg[j] = Wt + (size_t)(n0 + wv * BRW + j * 8 + lr8) * K + (cpos ^ lr8) * 8;

  const int xa = quad ^ (col & 7);
  const int niter = K / 64;

#pragma unroll
  for (int j = 0; j < AJ; ++j)
    GLOAD_LDS16(ag[j], ldsA0 + (wv * ARW + j * 8) * 64);
#pragma unroll
  for (int j = 0; j < BJ; ++j)
    GLOAD_LDS16(bg[j], ldsB0 + (wv * BRW + j * 8) * 64);

  for (int it = 0; it < niter; ++it) {
    __syncthreads();
    const bf16_t* cA = (it & 1) ? ldsA1 : ldsA0;
    const bf16_t* cB = (it & 1) ? ldsB1 : ldsB0;
    if (it + 1 < niter) {
      bf16_t* nA = (it & 1) ? ldsA0 : ldsA1;
      bf16_t* nB = (it & 1) ? ldsB0 : ldsB1;
      const int off = (it + 1) * 64;
#pragma unroll
      for (int j = 0; j < AJ; ++j)
        GLOAD_LDS16(ag[j] + off, nA + (wv * ARW + j * 8) * 64);
#pragma unroll
      for (int j = 0; j < BJ; ++j)
        GLOAD_LDS16(bg[j] + off, nB + (wv * BRW + j * 8) * 64);
    }
#pragma unroll
    for (int ks = 0; ks < 2; ++ks) {
      const int xk = (xa ^ (ks * 4)) * 8;
      bf16x8 af[MI], bfr[NI];
#pragma unroll
      for (int mi = 0; mi < MI; ++mi)
        af[mi] = *(const bf16x8*)(cA + (wm * (MI * 16) + mi * 16 + col) * 64 + xk);
#pragma unroll
      for (int ni = 0; ni < NI; ++ni)
        bfr[ni] = *(const bf16x8*)(cB + (wn * (NI * 16) + ni * 16 + col) * 64 + xk);
#pragma unroll
      for (int mi = 0; mi < MI; ++mi)
#pragma unroll
        for (int ni = 0; ni < NI; ++ni)
          acc[mi][ni] = MFMA16(af[mi], bfr[ni], acc[mi][ni]);
    }
  }
}

// ---------------------------------------------------------------------------
// Kernel 1: QKV GEMM — retiled 128x64 (48 KB LDS -> 3 blocks/CU resident,
// 1536 blocks queued; the K-loop is latency-bound at 2/CU).  One head per
// block on the V side.  Q pre-scaled by QSCALE.  V: LDS-bounce transpose
// with per-64-tile key permutation sigma(t) = (t&15)*4 + ((t>>4)&3).
// ---------------------------------------------------------------------------
__global__ __launch_bounds__(256) void qkv_gemm_kernel(
    const bf16_t* __restrict__ x, const bf16_t* __restrict__ w,
    const float* __restrict__ bias,
    bf16_t* __restrict__ qws, bf16_t* __restrict__ kws, bf16_t* __restrict__ vws)
{
  __shared__ __align__(16) bf16_t ldsA[2][128 * 64];   // 32 KB
  __shared__ __align__(16) bf16_t ldsB[2][64 * 64];    // 16 KB
  const int lane = threadIdx.x & 63;
  const int wv   = threadIdx.x >> 6;
  const int col  = lane & 15;
  const int quad = lane >> 4;
  const int wm = wv >> 1, wn = wv & 1;
  const int m0 = blockIdx.y * 128;
  const int n0 = blockIdx.x * 64;

  f32x4 acc[4][2] = {};
  gemm_mainloop_db<128, 64, 4, 2>(x, w, C, m0, n0,
                                  ldsA[0], ldsA[1], ldsB[0], ldsB[1], acc);

  const int which = n0 >> 10;          // block-uniform: 0=Q, 1=K, 2=V

  if (which == 2) {
    // ---- V path: LDS-bounce transpose (wave tile 64 t x 32 d) ----
    __syncthreads();                   // mainloop readers done; reuse ldsA
    bf16_t* vt = &ldsA[0][0] + wv * 2048;   // 4 KB wave-private region

#pragma unroll
    for (int ni = 0; ni < 2; ++ni) {
      const int n = n0 + wn * 32 + ni * 16 + col;
      const float bval = bias[n];
      const int dl = ni * 16 + col;    // 0..31 within wave region
#pragma unroll
      for (int r = 0; r < 4; ++r) {
        bf16x4 pw;
#pragma unroll
        for (int mi = 0; mi < 4; ++mi)
          pw[mi] = (bf16_t)(acc[mi][ni][r] + bval);
        // sigma base = (quad*4+r)*4; chunk k = (quad*4+r)>>1
        const int k = 2 * quad + (r >> 1);
        const int S = dl * 8 + (k ^ (dl & 7));
        *(bf16x4*)(vt + S * 8 + (r & 1) * 4) = pw;
      }
    }

    const int b   = (m0 + wm * 64) >> 11;
    const int t0w = (m0 + wm * 64) & (T - 1);    // 64-aligned
    const int h   = (n0 & (C - 1)) >> 6;         // one head per block
    const size_t bh = (size_t)(b * H + h);
    const int lr8 = lane >> 3;
    const int c8  = lane & 7;
#pragma unroll
    for (int j = 0; j < 4; ++j) {
      const int dl = j * 8 + lr8;                // 0..31
      const int d  = wn * 32 + dl;
      bf16x8 row = *(const bf16x8*)(vt + (dl * 8 + (c8 ^ (dl & 7))) * 8);
      *(bf16x8*)(vws + (bh * D + d) * T + t0w + c8 * 8) = row;
    }
  } else {
    // ---- Q/K path ----
#pragma unroll
    for (int ni = 0; ni < 2; ++ni) {
      const int n = n0 + wn * 32 + ni * 16 + col;
      const float bval = bias[n];
      const int c = n & (C - 1);
      const int h = c >> 6;
      const int d = c & 63;
#pragma unroll
      for (int mi = 0; mi < 4; ++mi) {
#pragma unroll
        for (int r = 0; r < 4; ++r) {
          const int m = m0 + wm * 64 + mi * 16 + quad * 4 + r;
          const int b = m >> 11;
          const int t = m & (T - 1);
          const size_t bh = (size_t)(b * H + h);
          if (which == 0)
            qws[(bh * T + t) * D + d] = (bf16_t)((acc[mi][ni][r] + bval) * QSCALE);
          else
            kws[(bh * T + t) * D + d] = (bf16_t)(acc[mi][ni][r] + bval);
        }
      }
    }
  }
}

// ---------------------------------------------------------------------------
// Kernel 2: causal flash attention (unchanged from round 15).
// ---------------------------------------------------------------------------
__global__ __launch_bounds__(256) void attn_kernel(
    const bf16_t* __restrict__ qws, const bf16_t* __restrict__ kws,
    const bf16_t* __restrict__ vws, bf16_t* __restrict__ yws)
{
  const int id = blockIdx.x;
  const int bh = id & 31;
  const int pr = id >> 5;            // 0..15
  const int tid  = threadIdx.x;
  const int wv   = tid >> 6;
  const int lane = tid & 63;
  const int col  = lane & 15;
  const int quad = lane >> 4;

  const bf16_t* Q  = qws + (size_t)bh * T * D;
  const bf16_t* K  = kws + (size_t)bh * T * D;
  const bf16_t* Vt = vws + (size_t)bh * D * T;

  __shared__ __align__(16) bf16_t ldsK[2][64 * 64];
  __shared__ __align__(16) bf16_t ldsV[2][64 * 64];
  __shared__ __align__(16) bf16_t ldsP[4][16 * 64];
  bf16_t* ldsPw = ldsP[wv];

  const int xs   = col & 7;
  const int cxq  = (quad ^ xs) * 8;
  const int lr8  = lane >> 3;
  const int ksrc = (lane & 7) ^ lr8;
  const int pxor = (quad & 1) * 4;
  const int b = bh >> 4;
  const int h = bh & 15;

  const int qt_h = 31 - pr, qt_l = pr;       // qt_l < qt_h always
  const int t0h = qt_h * 64, t0l = qt_l * 64;
  const int twh = t0h + 16 * wv, twl = t0l + 16 * wv;
  const int niter = qt_h + 1;

  bf16x8 qfh0 = *(const bf16x8*)(Q + (size_t)(twh + col) * D + quad * 8);
  bf16x8 qfh1 = *(const bf16x8*)(Q + (size_t)(twh + col) * D + 32 + quad * 8);
  bf16x8 qfl0 = *(const bf16x8*)(Q + (size_t)(twl + col) * D + quad * 8);
  bf16x8 qfl1 = *(const bf16x8*)(Q + (size_t)(twl + col) * D + 32 + quad * 8);

  f32x4 oh[4] = {}, ol[4] = {};
  f32x4 lph = {}, lpl = {};

  auto compute_tile = [&](const bf16_t* bK, const bf16_t* bV, int s0, int tw,
                          int t0, bf16x8 qf0, bf16x8 qf1,
                          f32x4 (&o)[4], f32x4& lp) {
    f32x4 sc[4];
#pragma unroll
    for (int kb = 0; kb < 4; ++kb) {
      const bf16_t* kr = bK + (kb * 16 + col) * 64;
      bf16x8 kf0 = *(const bf16x8*)(kr + cxq);
      bf16x8 kf1 = *(const bf16x8*)(kr + (cxq ^ 32));
      f32x4 a = {};
      a = MFMA16(qf0, kf0, a);
      a = MFMA16(qf1, kf1, a);
      sc[kb] = a;
    }
    if (s0 == t0) {          // diagonal tile: masked softmax (uniform branch)
#pragma unroll
      for (int r = 0; r < 4; ++r) {
        const int prow = (quad * 4 + r) * 64;
        const int pxr  = pxor + r;
        bf16x4 pw;
#pragma unroll
        for (int kb = 0; kb < 4; ++kb) {
          float p = __builtin_amdgcn_exp2f(sc[kb][r]);
          if (s0 + kb * 16 + col > tw + quad * 4 + r) p = 0.0f;
          lp[r] += p;
          pw[kb] = (bf16_t)p;
        }
        *(bf16x4*)(ldsPw + prow + (((col >> 1) ^ pxr) * 8) + (col & 1) * 4) = pw;
      }
    } else {                 // interior tile: clean path
#pragma unroll
      for (int r = 0; r < 4; ++r) {
        const int prow = (quad * 4 + r) * 64;
        const int pxr  = pxor + r;
        bf16x4 pw;
#pragma unroll
        for (int kb = 0; kb < 4; ++kb) {
          float p = __builtin_amdgcn_exp2f(sc[kb][r]);
          lp[r] += p;
          pw[kb] = (bf16_t)p;
        }
        *(bf16x4*)(ldsPw + prow + (((col >> 1) ^ pxr) * 8) + (col & 1) * 4) = pw;
      }
    }
#pragma unroll
    for (int ks = 0; ks < 2; ++ks) {
      const int xk = cxq ^ (ks * 32);
      bf16x8 pa = *(const bf16x8*)(ldsPw + col * 64 + xk);
#pragma unroll
      for (int ni = 0; ni < 4; ++ni) {
        bf16x8 vf = *(const bf16x8*)(bV + (ni * 16 + col) * 64 + xk);
        o[ni] = MFMA16(pa, vf, o[ni]);
      }
    }
  };

  // prologue: stage tile 0 into buffer 0
#pragma unroll
  for (int j = 0; j < 2; ++j) {
    GLOAD_LDS16(K + (size_t)(16 * wv + j * 8 + lr8) * D + ksrc * 8,
                ldsK[0] + (16 * wv + j * 8) * 64);
    GLOAD_LDS16(Vt + (size_t)(16 * wv + j * 8 + lr8) * T + ksrc * 8,
                ldsV[0] + (16 * wv + j * 8) * 64);
  }

  for (int it = 0; it < niter; ++it) {
    const int s0 = it * 64;
    __syncthreads();

    if (it + 1 < niter) {
      const int sn = s0 + 64;
      bf16_t* dK = ldsK[(it + 1) & 1];
      bf16_t* dV = ldsV[(it + 1) & 1];
#pragma unroll
      for (int j = 0; j < 2; ++j) {
        GLOAD_LDS16(K + (size_t)(sn + 16 * wv + j * 8 + lr8) * D + ksrc * 8,
                    dK + (16 * wv + j * 8) * 64);
        GLOAD_LDS16(Vt + (size_t)(16 * wv + j * 8 + lr8) * T + sn + ksrc * 8,
                    dV + (16 * wv + j * 8) * 64);
      }
    }

    const bf16_t* bK = ldsK[it & 1];
    const bf16_t* bV = ldsV[it & 1];

    compute_tile(bK, bV, s0, twh, t0h, qfh0, qfh1, oh, lph);
    if (s0 <= t0l)
      compute_tile(bK, bV, s0, twl, t0l, qfl0, qfl1, ol, lpl);
  }

  // epilogue: reduce l, normalize, write Y for both tiles
#pragma unroll
  for (int r = 0; r < 4; ++r) {
    float l0 = lph[r], l1 = lpl[r];
#pragma unroll
    for (int off = 1; off < 16; off <<= 1) {
      l0 += __shfl_xor(l0, off);
      l1 += __shfl_xor(l1, off);
    }
    const float rl0 = 1.0f / l0, rl1 = 1.0f / l1;
    const int th = twh + quad * 4 + r;
    const int tl = twl + quad * 4 + r;
#pragma unroll
    for (int ni = 0; ni < 4; ++ni) {
      const int d = ni * 16 + col;
      yws[((size_t)(b * T + th)) * C + h * D + d] = (bf16_t)(oh[ni][r] * rl0);
      yws[((size_t)(b * T + tl)) * C + h * D + d] = (bf16_t)(ol[ni][r] * rl1);
    }
  }
}

// ---------------------------------------------------------------------------
// Kernel 3: output projection — 64x64 tiles (1024 blocks = 4/CU), dbuf
// mainloop, f32 output (unchanged from round 15).
// ---------------------------------------------------------------------------
__global__ __launch_bounds__(256) void proj_gemm_kernel(
    const bf16_t* __restrict__ y, const bf16_t* __restrict__ w,
    const float* __restrict__ bias, float* __restrict__ out)
{
  __shared__ __align__(16) bf16_t ldsA[2][64 * 64];
  __shared__ __align__(16) bf16_t ldsB[2][64 * 64];
  const int lane = threadIdx.x & 63;
  const int wv   = threadIdx.x >> 6;
  const int col  = lane & 15;
  const int quad = lane >> 4;
  const int wm = wv >> 1, wn = wv & 1;
  const int m0 = blockIdx.y * 64;
  const int n0 = blockIdx.x * 64;

  f32x4 acc[2][2] = {};
  gemm_mainloop_db<64, 64, 2, 2>(y, w, C, m0, n0,
                                 ldsA[0], ldsA[1], ldsB[0], ldsB[1], acc);

#pragma unroll
  for (int ni = 0; ni < 2; ++ni) {
    const int n = n0 + wn * 32 + ni * 16 + col;
    const float bval = bias[n];
#pragma unroll
    for (int mi = 0; mi < 2; ++mi) {
#pragma unroll
      for (int r = 0; r < 4; ++r) {
        const int m = m0 + wm * 32 + mi * 16 + quad * 4 + r;
        out[(size_t)m * C + n] = acc[mi][ni][r] + bval;
      }
    }
  }
}

// ---------------------------------------------------------------------------
extern "C" void kernel_launch(void* const* d_in, const int* in_sizes, int n_in,
                              void* d_out, int out_size, void* d_ws, size_t ws_size,
                              hipStream_t stream) {
  const float* x      = (const float*)d_in[0];
  const float* attn_w = (const float*)d_in[1];
  const float* attn_b = (const float*)d_in[2];
  const float* proj_w = (const float*)d_in[3];
  const float* proj_b = (const float*)d_in[4];
  float* out = (float*)d_out;

  const size_t E = (size_t)B * H * T * D;   // 4,194,304
  char* ws = (char*)d_ws;
  bf16_t* qws = (bf16_t*)(ws);
  bf16_t* kws = (bf16_t*)(ws + 2 * E);
  bf16_t* vws = (bf16_t*)(ws + 4 * E);
  bf16_t* yws = (bf16_t*)(ws + 6 * E);
  bf16_t* xb  = (bf16_t*)(ws + 8 * E);
  bf16_t* awb = (bf16_t*)(ws + 10 * E);
  bf16_t* pwb = (bf16_t*)(ws + 11 * E + E / 2);

  const int NX = M * C, NAW = NQKV * C, NPW = C * C;
  cvt_kernel<<<dim3(NX / 2048, 3), 256, 0, stream>>>(
      x, xb, NX, attn_w, awb, NAW, proj_w, pwb, NPW);
  qkv_gemm_kernel<<<dim3(NQKV / 64, M / 128), 256, 0, stream>>>(
      xb, awb, attn_b, qws, kws, vws);
  attn_kernel<<<512, 256, 0, stream>>>(qws, kws, vws, yws);
  proj_gemm_kernel<<<dim3(C / 64, M / 64), 256, 0, stream>>>(
      yws, pwb, proj_b, out);
}